// Round 1
// baseline (452.192 us; speedup 1.0000x reference)
//
#include <hip/hip_runtime.h>

// SSIM of raw vs dst, (32,3,512,512) fp32, crop 4, 11x11 Gaussian (sigma=1.5),
// per-batch mean -> float[32].
//
// Design: separable Gaussian (outer(g,g)) => horizontal 11-tap into LDS for 5
// fields (r, d, r^2, d^2, r*d), then vertical 11-tap + SSIM formula + block
// reduction + one atomicAdd per block into d_ws accumulators. 255-scaling is
// folded into the moments after the conv (conv is linear).

#define IMG   512
#define OUTD  494          // 512 - 2*4 - 10
#define CB    4
#define NTAP  11
#define TW    64           // output tile width
#define TH    32           // output tile height
#define HALO  (NTAP - 1)
#define C1F   6.5025f      // (0.01*255)^2
#define C2F   58.5225f     // (0.03*255)^2
#define NPIX  732108.0f    // 3*494*494

__global__ void ssim_zero(float* __restrict__ accum) {
    if (threadIdx.x < 32) accum[threadIdx.x] = 0.0f;
}

__global__ __launch_bounds__(256) void ssim_main(
        const float* __restrict__ raw, const float* __restrict__ dst,
        float* __restrict__ accum) {
    // hs[field][row][x]: horizontal conv results. 5*42*64*4B = 52.5 KB.
    __shared__ float hs[5][TH + HALO][TW];
    __shared__ float red[4];

    const int tid = threadIdx.x;
    const int lx  = tid & 63;   // lane / tile column
    const int lr  = tid >> 6;   // wave id 0..3 / row group
    const int bc  = blockIdx.z;     // b*3 + c
    const int b   = bc / 3;
    const int ty0 = blockIdx.y * TH;
    const int tx0 = blockIdx.x * TW;

    // Gaussian weights, matching jnp: g = exp(-x^2/(2*1.5^2)); g /= sum(g)
    float gw[NTAP];
    {
        float s = 0.0f;
        #pragma unroll
        for (int k = 0; k < NTAP; ++k) {
            float x = (float)(k - (NTAP - 1) / 2);
            gw[k] = expf(-x * x * (1.0f / 4.5f));
            s += gw[k];
        }
        float inv = 1.0f / s;
        #pragma unroll
        for (int k = 0; k < NTAP; ++k) gw[k] *= inv;
    }

    const float* rbase = raw + (size_t)bc * (IMG * IMG);
    const float* dbase = dst + (size_t)bc * (IMG * IMG);

    // Stage A: horizontal 11-tap conv of 5 fields, direct from global (L1/L2
    // serve the k-overlap; lanes are consecutive in x => coalesced).
    for (int r = lr; r < TH + HALO; r += 4) {
        int row = ty0 + r + CB;
        if (row > IMG - 1) row = IMG - 1;             // clamp (edge tiles; values unused)
        const float* rrow = rbase + (size_t)row * IMG;
        const float* drow = dbase + (size_t)row * IMG;
        const int cb0 = tx0 + lx + CB;
        float hr = 0.f, hd = 0.f, hrr = 0.f, hdd = 0.f, hrd = 0.f;
        #pragma unroll
        for (int k = 0; k < NTAP; ++k) {
            int col = cb0 + k;
            if (col > IMG - 1) col = IMG - 1;         // clamp (edge tiles; values unused)
            float a = rrow[col];
            float c = drow[col];
            float w = gw[k];
            float wa = w * a, wc = w * c;
            hr += wa;
            hd += wc;
            hrr = fmaf(wa, a, hrr);
            hdd = fmaf(wc, c, hdd);
            hrd = fmaf(wa, c, hrd);
        }
        hs[0][r][lx] = hr;
        hs[1][r][lx] = hd;
        hs[2][r][lx] = hrr;
        hs[3][r][lx] = hdd;
        hs[4][r][lx] = hrd;
    }
    __syncthreads();

    // Stage B: vertical 11-tap + SSIM.
    float acc = 0.0f;
    const int ox = tx0 + lx;
    for (int yy = lr; yy < TH; yy += 4) {
        int oy = ty0 + yy;
        float mr = 0.f, md = 0.f, mrr = 0.f, mdd = 0.f, mrd = 0.f;
        #pragma unroll
        for (int k = 0; k < NTAP; ++k) {
            float w = gw[k];
            mr  = fmaf(w, hs[0][yy + k][lx], mr);
            md  = fmaf(w, hs[1][yy + k][lx], md);
            mrr = fmaf(w, hs[2][yy + k][lx], mrr);
            mdd = fmaf(w, hs[3][yy + k][lx], mdd);
            mrd = fmaf(w, hs[4][yy + k][lx], mrd);
        }
        if (oy < OUTD && ox < OUTD) {
            // fold the 255 scaling in now (linear conv => scale moments)
            mr  *= 255.0f;   md  *= 255.0f;
            mrr *= 65025.0f; mdd *= 65025.0f; mrd *= 65025.0f;
            float mr2 = mr * mr, md2 = md * md, mprod = mr * md;
            float vr = mrr - mr2, vd = mdd - md2, cov = mrd - mprod;
            float num = (2.0f * mprod + C1F) * (2.0f * cov + C2F);
            float den = (mr2 + md2 + C1F) * (vr + vd + C2F);
            acc += num / den;
        }
    }

    // wave-64 shuffle reduce, then cross-wave via LDS, one atomic per block
    #pragma unroll
    for (int off = 32; off > 0; off >>= 1)
        acc += __shfl_down(acc, off, 64);
    if (lx == 0) red[lr] = acc;
    __syncthreads();
    if (tid == 0) {
        float t = red[0] + red[1] + red[2] + red[3];
        atomicAdd(&accum[b], t);
    }
}

__global__ void ssim_final(const float* __restrict__ accum, float* __restrict__ out) {
    int i = threadIdx.x;
    if (i < 32) out[i] = accum[i] * (1.0f / NPIX);
}

extern "C" void kernel_launch(void* const* d_in, const int* in_sizes, int n_in,
                              void* d_out, int out_size, void* d_ws, size_t ws_size,
                              hipStream_t stream) {
    const float* raw = (const float*)d_in[0];
    const float* dst = (const float*)d_in[1];
    float* out   = (float*)d_out;
    float* accum = (float*)d_ws;   // 32 fp32 batch accumulators

    ssim_zero<<<1, 64, 0, stream>>>(accum);
    dim3 grid((OUTD + TW - 1) / TW,   // 8
              (OUTD + TH - 1) / TH,   // 16
              96);                    // 32 batches * 3 channels
    ssim_main<<<grid, 256, 0, stream>>>(raw, dst, accum);
    ssim_final<<<1, 64, 0, stream>>>(accum, out);
}

// Round 2
// 278.279 us; speedup vs baseline: 1.6250x; 1.6250x over previous
//
#include <hip/hip_runtime.h>

// SSIM (32,3,512,512) fp32, crop 4, 11x11 Gaussian sigma=1.5, per-batch mean.
//
// V2: vertical-first separable conv.
//  Stage A: vertical 11-tap of 5 moment fields (r, d, r2, d2, rd) from GLOBAL
//           (coalesced float4 rows, no y-halo between blocks), 2 rows x 4 cols
//           per task, results to LDS vs[5][32][80].
//  Stage B: horizontal 11-tap from LDS via 4x ds_read_b128 sliding window
//           (4 outputs per 20 b128 reads), SSIM formula, block partial ->
//           unique d_ws slot (no atomics, no zero kernel).

#define IMG   512
#define OUTD  494
#define CB    4
#define TW    64
#define TH    32
#define VSW   80           // padded LDS row width (74 used)
#define C1F   6.5025f
#define C2F   58.5225f
#define NPIX  732108.0f    // 3*494*494
#define XBLK  8
#define YBLK  16
#define SLOTS 384          // XBLK*YBLK*3 partials per batch

__global__ __launch_bounds__(256) void ssim_main(
        const float* __restrict__ raw, const float* __restrict__ dst,
        float* __restrict__ partial) {
    __shared__ float vs[5][TH][VSW];   // 51.2 KB
    __shared__ float red[4];

    const int tid = threadIdx.x;
    const int bc  = blockIdx.z;
    const int b   = bc / 3;
    const int c3  = bc - b * 3;
    const int ty0 = blockIdx.y * TH;
    const int tx0 = blockIdx.x * TW;

    // Gaussian weights: g = exp(-x^2/(2*1.5^2)); g /= sum(g)  (matches jnp)
    float gw[11];
    {
        float s = 0.f;
        #pragma unroll
        for (int k = 0; k < 11; ++k) {
            float x = (float)(k - 5);
            gw[k] = expf(-x * x * (1.0f / 4.5f));
            s += gw[k];
        }
        float inv = 1.0f / s;
        #pragma unroll
        for (int k = 0; k < 11; ++k) gw[k] *= inv;
    }

    const float* rb = raw + (size_t)bc * (IMG * IMG);
    const float* db = dst + (size_t)bc * (IMG * IMG);

    // ---- Stage A: vertical conv. 304 tasks = 16 row-pairs x 19 x-groups. ----
    #pragma unroll 1
    for (int t = tid; t < 304; t += 256) {
        const int rp = t / 19;
        const int xg = t - rp * 19;
        int col0 = CB + tx0 + xg * 4;
        if (col0 > IMG - 4) col0 = IMG - 4;    // edge blocks: garbage cols unused
        const int row0 = CB + ty0 + rp * 2;

        float a0[5][4] = {{0.f}};   // moments for vs-row rp*2
        float a1[5][4] = {{0.f}};   // moments for vs-row rp*2+1
        #pragma unroll
        for (int k = 0; k < 12; ++k) {
            int r = row0 + k;
            if (r > IMG - 1) r = IMG - 1;      // bottom edge: rows unused
            const float4 va = *(const float4*)(rb + (size_t)r * IMG + col0);
            const float4 vc = *(const float4*)(db + (size_t)r * IMG + col0);
            const float A[4]  = {va.x, va.y, va.z, va.w};
            const float Cv[4] = {vc.x, vc.y, vc.z, vc.w};
            float p2[4], q2[4], pq[4];
            #pragma unroll
            for (int c = 0; c < 4; ++c) {
                p2[c] = A[c] * A[c];
                q2[c] = Cv[c] * Cv[c];
                pq[c] = A[c] * Cv[c];
            }
            if (k < 11) {
                const float w = gw[k];
                #pragma unroll
                for (int c = 0; c < 4; ++c) {
                    a0[0][c] = fmaf(w, A[c],  a0[0][c]);
                    a0[1][c] = fmaf(w, Cv[c], a0[1][c]);
                    a0[2][c] = fmaf(w, p2[c], a0[2][c]);
                    a0[3][c] = fmaf(w, q2[c], a0[3][c]);
                    a0[4][c] = fmaf(w, pq[c], a0[4][c]);
                }
            }
            if (k >= 1) {
                const float w = gw[k - 1];
                #pragma unroll
                for (int c = 0; c < 4; ++c) {
                    a1[0][c] = fmaf(w, A[c],  a1[0][c]);
                    a1[1][c] = fmaf(w, Cv[c], a1[1][c]);
                    a1[2][c] = fmaf(w, p2[c], a1[2][c]);
                    a1[3][c] = fmaf(w, q2[c], a1[3][c]);
                    a1[4][c] = fmaf(w, pq[c], a1[4][c]);
                }
            }
        }
        #pragma unroll
        for (int f = 0; f < 5; ++f) {
            *(float4*)&vs[f][rp * 2 + 0][xg * 4] =
                make_float4(a0[f][0], a0[f][1], a0[f][2], a0[f][3]);
            *(float4*)&vs[f][rp * 2 + 1][xg * 4] =
                make_float4(a1[f][0], a1[f][1], a1[f][2], a1[f][3]);
        }
    }
    __syncthreads();

    // ---- Stage B: horizontal conv + SSIM. Thread = 4 cols x 2 rows. ----
    const int xg  = tid & 15;
    const int yt  = tid >> 4;
    const int ox0 = tx0 + xg * 4;
    float ssum = 0.f;
    #pragma unroll
    for (int r2 = 0; r2 < 2; ++r2) {
        const int row = yt * 2 + r2;
        const int oy  = ty0 + row;
        float m[5][4];
        #pragma unroll
        for (int f = 0; f < 5; ++f) {
            const float4* vp = (const float4*)&vs[f][row][xg * 4];
            const float4 A = vp[0], B = vp[1], Cq = vp[2], D = vp[3];
            const float win[16] = {A.x, A.y, A.z, A.w, B.x, B.y, B.z, B.w,
                                   Cq.x, Cq.y, Cq.z, Cq.w, D.x, D.y, D.z, D.w};
            #pragma unroll
            for (int c = 0; c < 4; ++c) {
                float o = 0.f;
                #pragma unroll
                for (int k = 0; k < 11; ++k) o = fmaf(gw[k], win[c + k], o);
                m[f][c] = o;
            }
        }
        if (oy < OUTD) {
            #pragma unroll
            for (int c = 0; c < 4; ++c) {
                if (ox0 + c < OUTD) {
                    const float mr  = m[0][c] * 255.0f;
                    const float md  = m[1][c] * 255.0f;
                    const float mrr = m[2][c] * 65025.0f;
                    const float mdd = m[3][c] * 65025.0f;
                    const float mrd = m[4][c] * 65025.0f;
                    const float mr2 = mr * mr, md2 = md * md, mpr = mr * md;
                    const float num = (2.0f * mpr + C1F) * (2.0f * (mrd - mpr) + C2F);
                    const float den = (mr2 + md2 + C1F) * ((mrr - mr2) + (mdd - md2) + C2F);
                    ssum += num / den;
                }
            }
        }
    }

    // block reduction -> unique partial slot (no atomics)
    #pragma unroll
    for (int off = 32; off > 0; off >>= 1)
        ssum += __shfl_down(ssum, off, 64);
    const int lane = tid & 63, wv = tid >> 6;
    if (lane == 0) red[wv] = ssum;
    __syncthreads();
    if (tid == 0) {
        const float t = red[0] + red[1] + red[2] + red[3];
        partial[(size_t)b * SLOTS + (blockIdx.y * gridDim.x + blockIdx.x) * 3 + c3] = t;
    }
}

__global__ __launch_bounds__(128) void ssim_final(
        const float* __restrict__ partial, float* __restrict__ out) {
    __shared__ float red[2];
    const int b = blockIdx.x, tid = threadIdx.x;
    float s = 0.f;
    for (int i = tid; i < SLOTS; i += 128) s += partial[(size_t)b * SLOTS + i];
    #pragma unroll
    for (int off = 32; off > 0; off >>= 1) s += __shfl_down(s, off, 64);
    if ((tid & 63) == 0) red[tid >> 6] = s;
    __syncthreads();
    if (tid == 0) out[b] = (red[0] + red[1]) * (1.0f / NPIX);
}

extern "C" void kernel_launch(void* const* d_in, const int* in_sizes, int n_in,
                              void* d_out, int out_size, void* d_ws, size_t ws_size,
                              hipStream_t stream) {
    const float* raw = (const float*)d_in[0];
    const float* dst = (const float*)d_in[1];
    float* out     = (float*)d_out;
    float* partial = (float*)d_ws;   // 32*384 fp32, fully overwritten each call

    dim3 grid(XBLK, YBLK, 96);       // 8 x 16 x (32 batches * 3 channels)
    ssim_main<<<grid, 256, 0, stream>>>(raw, dst, partial);
    ssim_final<<<32, 128, 0, stream>>>(partial, out);
}